// Round 8
// baseline (796.888 us; speedup 1.0000x reference)
//
#include <hip/hip_runtime.h>

#define NN 8192
#define FI 256
#define FO 128
#define GAT_ALPHA 0.2f

// ===== PROBE ROUND: k4 repeated 16x, k2 repeated 6x (bit-identical output) =====
#define K4_REPS 16
#define K2_REPS 6

typedef _Float16 f16x8 __attribute__((ext_vector_type(8)));
typedef _Float16 f16x2 __attribute__((ext_vector_type(2)));
typedef float f32x4 __attribute__((ext_vector_type(4)));
typedef unsigned char uchar;
typedef unsigned int uint32;

// ---------------------------------------------------------------------------
// K1: Wh[j][f] = sum_k h[j][k] * W[f][k] + b[f]   (fp32, LDS-tiled)
// ---------------------------------------------------------------------------
__global__ __launch_bounds__(256) void k1_wh(const float* __restrict__ h,
                                             const float* __restrict__ W,
                                             const float* __restrict__ bias,
                                             float* __restrict__ Wh) {
  __shared__ float hs[32][FI + 1];
  __shared__ float wt[32][FO];
  const int t = threadIdx.x;
  const int j0 = blockIdx.x * 32;
  {
    const int row = t >> 3, c0 = (t & 7) * 32;
    const float* src = h + (size_t)(j0 + row) * FI + c0;
#pragma unroll
    for (int e = 0; e < 8; ++e) {
      float4 v = *(const float4*)(src + 4 * e);
      hs[row][c0 + 4 * e + 0] = v.x;
      hs[row][c0 + 4 * e + 1] = v.y;
      hs[row][c0 + 4 * e + 2] = v.z;
      hs[row][c0 + 4 * e + 3] = v.w;
    }
  }
  const int f4 = (t & 31) * 4;
  const int r0 = (t >> 5) * 4;
  float acc[4][4];
#pragma unroll
  for (int r = 0; r < 4; ++r)
#pragma unroll
    for (int e = 0; e < 4; ++e) acc[r][e] = 0.f;

  for (int kc = 0; kc < FI; kc += 32) {
    __syncthreads();
    {
      const int f = t >> 1, kb = (t & 1) * 16;
      const float* wsrc = W + (size_t)f * FI + kc + kb;
#pragma unroll
      for (int e = 0; e < 16; ++e) wt[kb + e][f] = wsrc[e];
    }
    __syncthreads();
#pragma unroll
    for (int k = 0; k < 32; ++k) {
      const float4 wv = *(const float4*)&wt[k][f4];
      float hv[4];
#pragma unroll
      for (int r = 0; r < 4; ++r) hv[r] = hs[r0 + r][kc + k];
#pragma unroll
      for (int r = 0; r < 4; ++r) {
        acc[r][0] += hv[r] * wv.x;
        acc[r][1] += hv[r] * wv.y;
        acc[r][2] += hv[r] * wv.z;
        acc[r][3] += hv[r] * wv.w;
      }
    }
  }
  const float4 bv = *(const float4*)&bias[f4];
#pragma unroll
  for (int r = 0; r < 4; ++r) {
    float4 o;
    o.x = acc[r][0] + bv.x;
    o.y = acc[r][1] + bv.y;
    o.z = acc[r][2] + bv.z;
    o.w = acc[r][3] + bv.w;
    *(float4*)&Wh[(size_t)(j0 + r0 + r) * FO + f4] = o;
  }
}

// ---------------------------------------------------------------------------
// K1b: s1/s2 scores + exp tables; block 0 also zeroes corr (k3 runs later).
// ---------------------------------------------------------------------------
__global__ __launch_bounds__(256) void k1b_sv(const float* __restrict__ Wh,
                                              const float* __restrict__ a,
                                              float4* __restrict__ r4,
                                              float4* __restrict__ c4,
                                              float2* __restrict__ r2,
                                              uint32* __restrict__ c2h,
                                              float* __restrict__ s2x,
                                              float* __restrict__ corr) {
  if (blockIdx.x == 0 && threadIdx.x < FO) corr[threadIdx.x] = 0.f;
  const int lane = threadIdx.x & 63;
  const int j = blockIdx.x * 4 + (threadIdx.x >> 6);
  const float* row = Wh + (size_t)j * FO;
  const float w0 = row[lane], w1 = row[lane + 64];
  float s1 = w0 * a[lane] + w1 * a[lane + 64];
  float s2 = w0 * a[FO + lane] + w1 * a[FO + lane + 64];
#pragma unroll
  for (int o = 32; o >= 1; o >>= 1) {
    s1 += __shfl_xor(s1, o);
    s2 += __shfl_xor(s2, o);
  }
  if (lane == 0) {
    const float e1 = expf(s1), e1a = expf(GAT_ALPHA * s1);
    const float e2 = expf(s2), e2a = expf(GAT_ALPHA * s2);
    float4 rv; rv.x = s1; rv.y = e1; rv.z = e1a; rv.w = 0.f;
    float4 cv; cv.x = s2; cv.y = e2; cv.z = e2a; cv.w = 0.f;
    r4[j] = rv;
    c4[j] = cv;
    r2[j] = make_float2(e1, e1a);
    f16x2 cp; cp.x = (_Float16)e2; cp.y = (_Float16)e2a;
    c2h[j] = __builtin_bit_cast(uint32, cp);
    s2x[j] = s2;
  }
}

// ---------------------------------------------------------------------------
// K2: single pass over adj. PROBE: rep loop x K2_REPS, acc reset + keep-alive.
// ---------------------------------------------------------------------------
__global__ __launch_bounds__(256) void k2_stats(const int* __restrict__ adj,
                                                const float4* __restrict__ r4,
                                                const float* __restrict__ s2x,
                                                uchar* __restrict__ bitsB,
                                                float2* __restrict__ zpart) {
  __shared__ float4 rs[64];
  const int t = threadIdx.x;
  const int jc = blockIdx.x & 3;
  const int ic = blockIdx.x >> 2;
  const int i0 = ic * 64;
  const int j0 = jc * 2048 + t * 8;
  if (t < 64) rs[t] = r4[i0 + t];
  const float4 ca = *(const float4*)(s2x + j0);
  const float4 cb = *(const float4*)(s2x + j0 + 4);
  const float cx[8] = {ca.x, ca.y, ca.z, ca.w, cb.x, cb.y, cb.z, cb.w};
  float accP[8], accN[8];
  __syncthreads();
  const int4* ap = (const int4*)(adj + (size_t)i0 * NN + j0);
  uchar* bp = bitsB + (size_t)i0 * (NN / 8) + jc * 256 + t;
#pragma unroll 1
  for (int rep = 0; rep < K2_REPS; ++rep) {
    asm volatile("" ::: "memory");  // force adj reloads each rep
#pragma unroll
    for (int e = 0; e < 8; ++e) { accP[e] = 0.f; accN[e] = 0.f; }
    for (int ir = 0; ir < 64; ir += 8) {
      int4 av[8][2];
#pragma unroll
      for (int u = 0; u < 8; ++u) {
        av[u][0] = ap[(size_t)(ir + u) * (NN / 4)];
        av[u][1] = ap[(size_t)(ir + u) * (NN / 4) + 1];
      }
#pragma unroll
      for (int u = 0; u < 8; ++u) {
        const float4 ri = rs[ir + u];
        const int aa[8] = {av[u][0].x, av[u][0].y, av[u][0].z, av[u][0].w,
                           av[u][1].x, av[u][1].y, av[u][1].z, av[u][1].w};
        uint32 byte = 0;
#pragma unroll
        for (int e = 0; e < 8; ++e) {
          const bool act = aa[e] > 0;
          byte |= act ? (1u << e) : 0u;
          const bool pos = (ri.x + cx[e]) >= 0.f;
          accP[e] += (act && pos) ? ri.y : 0.f;
          accN[e] += (act && !pos) ? ri.z : 0.f;
        }
        bp[(size_t)(ir + u) * (NN / 8)] = (uchar)byte;
      }
    }
    asm volatile("" ::
                     "v"(accP[0]), "v"(accP[1]), "v"(accP[2]), "v"(accP[3]),
                     "v"(accP[4]), "v"(accP[5]), "v"(accP[6]), "v"(accP[7]),
                     "v"(accN[0]), "v"(accN[1]), "v"(accN[2]), "v"(accN[3]),
                     "v"(accN[4]), "v"(accN[5]), "v"(accN[6]), "v"(accN[7]));
  }
  float2* zp = zpart + (size_t)ic * NN + j0;
#pragma unroll
  for (int e = 0; e < 8; ++e) zp[e] = make_float2(accP[e], accN[e]);
}

// ---------------------------------------------------------------------------
// K3: Z_j from 128 partials; emit Wfrag in MFMA-B-fragment-major layout.
// ---------------------------------------------------------------------------
__global__ __launch_bounds__(256) void k3_scale(const float* __restrict__ Wh,
                                                const float4* __restrict__ c4,
                                                const float2* __restrict__ zpart,
                                                _Float16* __restrict__ Wfrag,
                                                float* __restrict__ corr) {
  __shared__ float rz[64];
  __shared__ int emp[64];
  __shared__ float2 psum[256];
  __shared__ __align__(16) _Float16 tile[FO * 64];
  const int t = threadIdx.x;
  const int j0 = blockIdx.x * 64;
  {
    const int jl = t & 63, q = t >> 6;
    float p = 0.f, n = 0.f;
    for (int ic = q * 32; ic < q * 32 + 32; ++ic) {
      const float2 z = zpart[(size_t)ic * NN + j0 + jl];
      p += z.x;
      n += z.y;
    }
    psum[t] = make_float2(p, n);
  }
  __syncthreads();
  if (t < 64) {
    const float p = psum[t].x + psum[64 + t].x + psum[128 + t].x + psum[192 + t].x;
    const float n = psum[t].y + psum[64 + t].y + psum[128 + t].y + psum[192 + t].y;
    const float4 cj = c4[j0 + t];
    const float Z = cj.y * p + cj.z * n;
    rz[t] = (Z > 0.f) ? 1.f / Z : 0.f;
    emp[t] = (Z > 0.f) ? 0 : 1;
  }
  __syncthreads();
  const int f = t & 127, half = t >> 7;
  const unsigned swf = (unsigned)((f & 7) << 4);
  for (int r = half; r < 64; r += 2) {
    const float v = Wh[(size_t)(j0 + r) * FO + f];
    *(_Float16*)((char*)tile + f * 128 + (((unsigned)(r * 2)) ^ swf)) =
        (_Float16)(v * rz[r]);
    if (emp[r]) atomicAdd(&corr[f], v * (1.f / 8192.f));
  }
  __syncthreads();
#pragma unroll
  for (int q = 0; q < 4; ++q) {
    const int G = t + 256 * q;
    const int kcfb = G >> 6, gl = G & 63;
    const int kc = kcfb >> 3, fb = kcfb & 7;
    const int gf = fb * 16 + (gl & 15);
    const int jloc = kc * 32 + (gl >> 4) * 8;
    const f16x8 v = *(const f16x8*)((const char*)tile + gf * 128 +
                                    (((unsigned)(jloc * 2)) ^ ((unsigned)((gf & 7) << 4))));
    ((f16x8*)Wfrag)[(size_t)(((j0 >> 5) + kc) * 8 + fb) * 64 + gl] = v;
  }
}

// ---------------------------------------------------------------------------
// K4: PROBE: whole pipeline x K4_REPS (acc reset per rep, store last rep).
// ---------------------------------------------------------------------------
#define BARRIER_LDS()                                          \
  do {                                                         \
    __builtin_amdgcn_sched_barrier(0);                         \
    asm volatile("s_waitcnt lgkmcnt(0)" ::: "memory");         \
    __builtin_amdgcn_s_barrier();                              \
    __builtin_amdgcn_sched_barrier(0);                         \
  } while (0)

__global__ __launch_bounds__(512, 4) void k4_main(const uchar* __restrict__ bitsB,
                                                  const float2* __restrict__ r2,
                                                  const uint32* __restrict__ c2h,
                                                  const _Float16* __restrict__ Wfrag,
                                                  float* __restrict__ part) {
  __shared__ __align__(16) _Float16 P[2][64 * 64];
  const int t = threadIdx.x;
  const int rowtile = blockIdx.x >> 2;
  const int kq = blockIdx.x & 3;
  const int rowbase = rowtile * 64;
  const int koff = kq * 2048;

  const int pr = t >> 3, jq = t & 7;
  const float2 rr = r2[rowbase + pr];
  const uchar* bp = bitsB + (size_t)(rowbase + pr) * (NN / 8) + (koff >> 3) + jq;
  const uint32* cp = c2h + koff + jq * 8;
  char* const pdst0 = (char*)&P[0][0] + pr * 128 + (((unsigned)(jq * 16)) ^ ((unsigned)((pr & 7) << 4)));
  char* const pdst1 = (char*)&P[1][0] + pr * 128 + (((unsigned)(jq * 16)) ^ ((unsigned)((pr & 7) << 4)));

  const int lane = t & 63, wave = t >> 6;
  const int wr = wave >> 2, wc = wave & 3;
  const int kgrp = lane >> 4, l15 = lane & 15;
  const unsigned asw = (unsigned)((l15 & 7) << 4);
  const int ar0 = (wr * 32 + l15) * 128;
  const int ar1 = ar0 + 16 * 128;

  f32x4 acc00, acc01, acc10, acc11;

  uchar mb0, mb1;
  uint32 c0a[4], c0b[4], c1a[4], c1b[4];
  f16x8 B000, B001, B010, B011, B100, B101, B110, B111;

#define LOADALL(S, MB, CA, CB, Bq00, Bq01, Bq10, Bq11)                              \
  do {                                                                              \
    MB = bp[(S) * 8];                                                               \
    const uint4 _ca = *(const uint4*)(cp + (S) * 64);                               \
    const uint4 _cb = *(const uint4*)(cp + (S) * 64 + 4);                           \
    CA[0] = _ca.x; CA[1] = _ca.y; CA[2] = _ca.z; CA[3] = _ca.w;                     \
    CB[0] = _cb.x; CB[1] = _cb.y; CB[2] = _cb.z; CB[3] = _cb.w;                     \
    const _Float16* _b = Wfrag + ((size_t)((kq * 64 + (S) * 2) * 8 + wc * 2) * 64 + lane) * 8; \
    Bq00 = *(const f16x8*)(_b);                                                     \
    Bq01 = *(const f16x8*)(_b + 512);                                               \
    Bq10 = *(const f16x8*)(_b + 4096);                                              \
    Bq11 = *(const f16x8*)(_b + 4096 + 512);                                        \
  } while (0)

#define PGEN(DST, MB, CA, CB)                                                       \
  do {                                                                              \
    union { f16x2 h[4]; f16x8 v; } U;                                               \
    _Pragma("unroll") for (int _p = 0; _p < 4; ++_p) {                              \
      const uint32 cv0 = (_p < 2) ? CA[2 * _p] : CB[2 * (_p - 2)];                  \
      const uint32 cv1 = (_p < 2) ? CA[2 * _p + 1] : CB[2 * (_p - 2) + 1];          \
      const f16x2 ch0 = __builtin_bit_cast(f16x2, cv0);                             \
      const f16x2 ch1 = __builtin_bit_cast(f16x2, cv1);                             \
      const float m0 = fmaxf(rr.x * (float)ch0.x, rr.y * (float)ch0.y);             \
      const float m1 = fmaxf(rr.x * (float)ch1.x, rr.y * (float)ch1.y);             \
      const float w0 = ((MB >> (2 * _p)) & 1) ? m0 : 0.f;                           \
      const float w1 = ((MB >> (2 * _p + 1)) & 1) ? m1 : 0.f;                       \
      U.h[_p] = __builtin_bit_cast(f16x2, __builtin_amdgcn_cvt_pkrtz(w0, w1));      \
    }                                                                               \
    *(f16x8*)(DST) = U.v;                                                           \
  } while (0)

#define DO_MFMA(BUF, Bq00, Bq01, Bq10, Bq11)                                        \
  do {                                                                              \
    const char* _Pb = (const char*)&P[BUF][0];                                      \
    const f16x8 a00 = *(const f16x8*)(_Pb + ar0 + ((((unsigned)(kgrp * 16))) ^ asw));        \
    const f16x8 a01 = *(const f16x8*)(_Pb + ar0 + (((unsigned)(64 + kgrp * 16)) ^ asw));     \
    const f16x8 a10 = *(const f16x8*)(_Pb + ar1 + ((((unsigned)(kgrp * 16))) ^ asw));        \
    const f16x8 a11 = *(const f16x8*)(_Pb + ar1 + (((unsigned)(64 + kgrp * 16)) ^ asw));     \
    __builtin_amdgcn_s_setprio(1);                                                  \
    acc00 = __builtin_amdgcn_mfma_f32_16x16x32_f16(a00, Bq00, acc00, 0, 0, 0);      \
    acc01 = __builtin_amdgcn_mfma_f32_16x16x32_f16(a00, Bq01, acc01, 0, 0, 0);      \
    acc10 = __builtin_amdgcn_mfma_f32_16x16x32_f16(a10, Bq00, acc10, 0, 0, 0);      \
    acc11 = __builtin_amdgcn_mfma_f32_16x16x32_f16(a10, Bq01, acc11, 0, 0, 0);      \
    acc00 = __builtin_amdgcn_mfma_f32_16x16x32_f16(a01, Bq10, acc00, 0, 0, 0);      \
    acc01 = __builtin_amdgcn_mfma_f32_16x16x32_f16(a01, Bq11, acc01, 0, 0, 0);      \
    acc10 = __builtin_amdgcn_mfma_f32_16x16x32_f16(a11, Bq10, acc10, 0, 0, 0);      \
    acc11 = __builtin_amdgcn_mfma_f32_16x16x32_f16(a11, Bq11, acc11, 0, 0, 0);      \
    __builtin_amdgcn_s_setprio(0);                                                  \
  } while (0)

#pragma unroll 1
  for (int rep = 0; rep < K4_REPS; ++rep) {
    acc00 = (f32x4){0.f, 0.f, 0.f, 0.f};
    acc01 = (f32x4){0.f, 0.f, 0.f, 0.f};
    acc10 = (f32x4){0.f, 0.f, 0.f, 0.f};
    acc11 = (f32x4){0.f, 0.f, 0.f, 0.f};

    LOADALL(0, mb0, c0a, c0b, B000, B001, B010, B011);
    LOADALL(1, mb1, c1a, c1b, B100, B101, B110, B111);
    PGEN(pdst0, mb0, c0a, c0b);
    BARRIER_LDS();

    for (int s = 0; s < 32; s += 2) {
      PGEN(pdst1, mb1, c1a, c1b);
      DO_MFMA(0, B000, B001, B010, B011);
      if (s + 2 < 32) LOADALL(s + 2, mb0, c0a, c0b, B000, B001, B010, B011);
      BARRIER_LDS();
      DO_MFMA(1, B100, B101, B110, B111);
      if (s + 2 < 32) PGEN(pdst0, mb0, c0a, c0b);
      if (s + 3 < 32) LOADALL(s + 3, mb1, c1a, c1b, B100, B101, B110, B111);
      BARRIER_LDS();
    }
    // keep this rep's MFMA results live (blocks DCE of non-final reps)
    asm volatile("" ::
                     "v"(acc00[0]), "v"(acc00[1]), "v"(acc00[2]), "v"(acc00[3]),
                     "v"(acc01[0]), "v"(acc01[1]), "v"(acc01[2]), "v"(acc01[3]),
                     "v"(acc10[0]), "v"(acc10[1]), "v"(acc10[2]), "v"(acc10[3]),
                     "v"(acc11[0]), "v"(acc11[1]), "v"(acc11[2]), "v"(acc11[3]));
  }

#undef LOADALL
#undef PGEN
#undef DO_MFMA

  const int orow = rowbase + wr * 32 + kgrp * 4;
  const int ocol = wc * 32 + l15;
  float* aP = part + (size_t)kq * NN * FO + (size_t)orow * FO + ocol;
#pragma unroll
  for (int r = 0; r < 4; ++r) {
    aP[(size_t)r * FO] = acc00[r];
    aP[(size_t)r * FO + 16] = acc01[r];
    aP[(size_t)(16 + r) * FO] = acc10[r];
    aP[(size_t)(16 + r) * FO + 16] = acc11[r];
  }
}

// ---------------------------------------------------------------------------
// K5: out = elu(sum_q part[q] + corr)
// ---------------------------------------------------------------------------
__global__ __launch_bounds__(256) void k5_fin(const float* __restrict__ part,
                                              const float* __restrict__ corr,
                                              float* __restrict__ out) {
  const int idx = blockIdx.x * 256 + threadIdx.x;
  const float4 p0 = ((const float4*)part)[idx];
  const float4 p1 = ((const float4*)(part + (size_t)NN * FO))[idx];
  const float4 p2 = ((const float4*)(part + (size_t)2 * NN * FO))[idx];
  const float4 p3 = ((const float4*)(part + (size_t)3 * NN * FO))[idx];
  const float4 c = ((const float4*)corr)[idx & 31];
  float4 v;
  v.x = p0.x + p1.x + p2.x + p3.x + c.x;
  v.y = p0.y + p1.y + p2.y + p3.y + c.y;
  v.z = p0.z + p1.z + p2.z + p3.z + c.z;
  v.w = p0.w + p1.w + p2.w + p3.w + c.w;
  v.x = (v.x > 0.f) ? v.x : (expf(v.x) - 1.f);
  v.y = (v.y > 0.f) ? v.y : (expf(v.y) - 1.f);
  v.z = (v.z > 0.f) ? v.z : (expf(v.z) - 1.f);
  v.w = (v.w > 0.f) ? v.w : (expf(v.w) - 1.f);
  ((float4*)out)[idx] = v;
}

// ---------------------------------------------------------------------------
extern "C" void kernel_launch(void* const* d_in, const int* in_sizes, int n_in,
                              void* d_out, int out_size, void* d_ws, size_t ws_size,
                              hipStream_t stream) {
  const float* h = (const float*)d_in[0];
  const int* adj = (const int*)d_in[1];
  const float* W = (const float*)d_in[2];
  const float* b = (const float*)d_in[3];
  const float* a = (const float*)d_in[4];
  float* out = (float*)d_out;
  char* ws = (char*)d_ws;

  float* Wh = (float*)(ws + 0);                                   // 4 MB  [k1..k3]
  _Float16* Wfrag = (_Float16*)(ws + 0x400000);                   // 2 MB  [k3..k4]
  uchar* bits = (uchar*)(ws + 0x600000);                          // 8 MB  [k2..k4]
  float2* zpart = (float2*)(ws + 0xE00000);                       // 8 MB  [k2..k3]
  float4* r4 = (float4*)(ws + 0x1600000);                         // 128 KB
  float4* c4 = (float4*)(ws + 0x1620000);                         // 128 KB
  float2* r2 = (float2*)(ws + 0x1640000);                         // 64 KB
  uint32* c2h = (uint32*)(ws + 0x1650000);                        // 32 KB
  float* s2x = (float*)(ws + 0x1658000);                          // 32 KB
  float* corr = (float*)(ws + 0x1660000);                         // 512 B
  float* part = (float*)(ws + 0x1700000);                         // 16 MB [k4..k5]

  k1_wh<<<NN / 32, 256, 0, stream>>>(h, W, b, Wh);
  k1b_sv<<<NN / 4, 256, 0, stream>>>(Wh, a, r4, c4, r2, c2h, s2x, corr);
  k2_stats<<<512, 256, 0, stream>>>(adj, r4, s2x, bits, zpart);
  k3_scale<<<NN / 64, 256, 0, stream>>>(Wh, c4, zpart, Wfrag, corr);
  k4_main<<<512, 512, 0, stream>>>(bits, r2, c2h, Wfrag, part);
  k5_fin<<<(NN * FO / 4) / 256, 256, 0, stream>>>(part, corr, out);
}

// Round 9
// 251.908 us; speedup vs baseline: 3.1634x; 3.1634x over previous
//
#include <hip/hip_runtime.h>

#define NN 8192
#define FI 256
#define FO 128
#define GAT_ALPHA 0.2f

typedef _Float16 f16x8 __attribute__((ext_vector_type(8)));
typedef _Float16 f16x2 __attribute__((ext_vector_type(2)));
typedef float f32x4 __attribute__((ext_vector_type(4)));
typedef unsigned char uchar;
typedef unsigned int uint32;

// ---------------------------------------------------------------------------
// K1: Wh[j][f] = sum_k h[j][k] * W[f][k] + b[f]   (fp32, LDS-tiled)
// ---------------------------------------------------------------------------
__global__ __launch_bounds__(256) void k1_wh(const float* __restrict__ h,
                                             const float* __restrict__ W,
                                             const float* __restrict__ bias,
                                             float* __restrict__ Wh) {
  __shared__ float hs[32][FI + 1];
  __shared__ float wt[32][FO];
  const int t = threadIdx.x;
  const int j0 = blockIdx.x * 32;
  {
    const int row = t >> 3, c0 = (t & 7) * 32;
    const float* src = h + (size_t)(j0 + row) * FI + c0;
#pragma unroll
    for (int e = 0; e < 8; ++e) {
      float4 v = *(const float4*)(src + 4 * e);
      hs[row][c0 + 4 * e + 0] = v.x;
      hs[row][c0 + 4 * e + 1] = v.y;
      hs[row][c0 + 4 * e + 2] = v.z;
      hs[row][c0 + 4 * e + 3] = v.w;
    }
  }
  const int f4 = (t & 31) * 4;
  const int r0 = (t >> 5) * 4;
  float acc[4][4];
#pragma unroll
  for (int r = 0; r < 4; ++r)
#pragma unroll
    for (int e = 0; e < 4; ++e) acc[r][e] = 0.f;

  for (int kc = 0; kc < FI; kc += 32) {
    __syncthreads();
    {
      const int f = t >> 1, kb = (t & 1) * 16;
      const float* wsrc = W + (size_t)f * FI + kc + kb;
#pragma unroll
      for (int e = 0; e < 16; ++e) wt[kb + e][f] = wsrc[e];
    }
    __syncthreads();
#pragma unroll
    for (int k = 0; k < 32; ++k) {
      const float4 wv = *(const float4*)&wt[k][f4];
      float hv[4];
#pragma unroll
      for (int r = 0; r < 4; ++r) hv[r] = hs[r0 + r][kc + k];
#pragma unroll
      for (int r = 0; r < 4; ++r) {
        acc[r][0] += hv[r] * wv.x;
        acc[r][1] += hv[r] * wv.y;
        acc[r][2] += hv[r] * wv.z;
        acc[r][3] += hv[r] * wv.w;
      }
    }
  }
  const float4 bv = *(const float4*)&bias[f4];
#pragma unroll
  for (int r = 0; r < 4; ++r) {
    float4 o;
    o.x = acc[r][0] + bv.x;
    o.y = acc[r][1] + bv.y;
    o.z = acc[r][2] + bv.z;
    o.w = acc[r][3] + bv.w;
    *(float4*)&Wh[(size_t)(j0 + r0 + r) * FO + f4] = o;
  }
}

// ---------------------------------------------------------------------------
// K1b: s1/s2 scores + exp tables; block 0 also zeroes corr (k3 runs later).
//  r4[j]=(s1, e^s1, e^.2s1, 0)  c4[j]=(s2, e^s2, e^.2s2, 0)
//  r2[j]=(e^s1, e^.2s1) f32     ey16[j]=f16 e^s2   ez16[j]=f16 e^.2s2
// ---------------------------------------------------------------------------
__global__ __launch_bounds__(256) void k1b_sv(const float* __restrict__ Wh,
                                              const float* __restrict__ a,
                                              float4* __restrict__ r4,
                                              float4* __restrict__ c4,
                                              float2* __restrict__ r2,
                                              _Float16* __restrict__ ey16,
                                              _Float16* __restrict__ ez16,
                                              float* __restrict__ s2x,
                                              float* __restrict__ corr) {
  if (blockIdx.x == 0 && threadIdx.x < FO) corr[threadIdx.x] = 0.f;
  const int lane = threadIdx.x & 63;
  const int j = blockIdx.x * 4 + (threadIdx.x >> 6);
  const float* row = Wh + (size_t)j * FO;
  const float w0 = row[lane], w1 = row[lane + 64];
  float s1 = w0 * a[lane] + w1 * a[lane + 64];
  float s2 = w0 * a[FO + lane] + w1 * a[FO + lane + 64];
#pragma unroll
  for (int o = 32; o >= 1; o >>= 1) {
    s1 += __shfl_xor(s1, o);
    s2 += __shfl_xor(s2, o);
  }
  if (lane == 0) {
    const float e1 = expf(s1), e1a = expf(GAT_ALPHA * s1);
    const float e2 = expf(s2), e2a = expf(GAT_ALPHA * s2);
    float4 rv; rv.x = s1; rv.y = e1; rv.z = e1a; rv.w = 0.f;
    float4 cv; cv.x = s2; cv.y = e2; cv.z = e2a; cv.w = 0.f;
    r4[j] = rv;
    c4[j] = cv;
    r2[j] = make_float2(e1, e1a);
    ey16[j] = (_Float16)e2;
    ez16[j] = (_Float16)e2a;
    s2x[j] = s2;
  }
}

// ---------------------------------------------------------------------------
// K2: single pass over adj (268 MB HBM floor). Thread owns 8 consecutive j
// (2x int4 = 32 B/lane), packs 8 activity bits into one byte, coalesced
// byte stores; 8 accP/accN register accumulators.
// ---------------------------------------------------------------------------
__global__ __launch_bounds__(256) void k2_stats(const int* __restrict__ adj,
                                                const float4* __restrict__ r4,
                                                const float* __restrict__ s2x,
                                                uchar* __restrict__ bitsB,
                                                float2* __restrict__ zpart) {
  __shared__ float4 rs[64];
  const int t = threadIdx.x;
  const int jc = blockIdx.x & 3;
  const int ic = blockIdx.x >> 2;
  const int i0 = ic * 64;
  const int j0 = jc * 2048 + t * 8;
  if (t < 64) rs[t] = r4[i0 + t];
  const float4 ca = *(const float4*)(s2x + j0);
  const float4 cb = *(const float4*)(s2x + j0 + 4);
  const float cx[8] = {ca.x, ca.y, ca.z, ca.w, cb.x, cb.y, cb.z, cb.w};
  float accP[8], accN[8];
#pragma unroll
  for (int e = 0; e < 8; ++e) { accP[e] = 0.f; accN[e] = 0.f; }
  __syncthreads();
  const int4* ap = (const int4*)(adj + (size_t)i0 * NN + j0);
  uchar* bp = bitsB + (size_t)i0 * (NN / 8) + jc * 256 + t;
  for (int ir = 0; ir < 64; ir += 8) {
    int4 av[8][2];
#pragma unroll
    for (int u = 0; u < 8; ++u) {
      av[u][0] = ap[(size_t)(ir + u) * (NN / 4)];
      av[u][1] = ap[(size_t)(ir + u) * (NN / 4) + 1];
    }
#pragma unroll
    for (int u = 0; u < 8; ++u) {
      const float4 ri = rs[ir + u];
      const int aa[8] = {av[u][0].x, av[u][0].y, av[u][0].z, av[u][0].w,
                         av[u][1].x, av[u][1].y, av[u][1].z, av[u][1].w};
      uint32 byte = 0;
#pragma unroll
      for (int e = 0; e < 8; ++e) {
        const bool act = aa[e] > 0;
        byte |= act ? (1u << e) : 0u;
        const bool pos = (ri.x + cx[e]) >= 0.f;
        accP[e] += (act && pos) ? ri.y : 0.f;
        accN[e] += (act && !pos) ? ri.z : 0.f;
      }
      bp[(size_t)(ir + u) * (NN / 8)] = (uchar)byte;
    }
  }
  float2* zp = zpart + (size_t)ic * NN + j0;
#pragma unroll
  for (int e = 0; e < 8; ++e) zp[e] = make_float2(accP[e], accN[e]);
}

// ---------------------------------------------------------------------------
// K3: Z_j from 128 partials; emit Wfrag in MFMA-B-fragment-major layout.
// Empty cols -> corr[f] (uniform softmax fix).
// ---------------------------------------------------------------------------
__global__ __launch_bounds__(256) void k3_scale(const float* __restrict__ Wh,
                                                const float4* __restrict__ c4,
                                                const float2* __restrict__ zpart,
                                                _Float16* __restrict__ Wfrag,
                                                float* __restrict__ corr) {
  __shared__ float rz[64];
  __shared__ int emp[64];
  __shared__ float2 psum[256];
  __shared__ __align__(16) _Float16 tile[FO * 64];
  const int t = threadIdx.x;
  const int j0 = blockIdx.x * 64;
  {
    const int jl = t & 63, q = t >> 6;
    float p = 0.f, n = 0.f;
    for (int ic = q * 32; ic < q * 32 + 32; ++ic) {
      const float2 z = zpart[(size_t)ic * NN + j0 + jl];
      p += z.x;
      n += z.y;
    }
    psum[t] = make_float2(p, n);
  }
  __syncthreads();
  if (t < 64) {
    const float p = psum[t].x + psum[64 + t].x + psum[128 + t].x + psum[192 + t].x;
    const float n = psum[t].y + psum[64 + t].y + psum[128 + t].y + psum[192 + t].y;
    const float4 cj = c4[j0 + t];
    const float Z = cj.y * p + cj.z * n;
    rz[t] = (Z > 0.f) ? 1.f / Z : 0.f;
    emp[t] = (Z > 0.f) ? 0 : 1;
  }
  __syncthreads();
  const int f = t & 127, half = t >> 7;
  const unsigned swf = (unsigned)((f & 7) << 4);
  for (int r = half; r < 64; r += 2) {
    const float v = Wh[(size_t)(j0 + r) * FO + f];
    *(_Float16*)((char*)tile + f * 128 + (((unsigned)(r * 2)) ^ swf)) =
        (_Float16)(v * rz[r]);
    if (emp[r]) atomicAdd(&corr[f], v * (1.f / 8192.f));
  }
  __syncthreads();
#pragma unroll
  for (int q = 0; q < 4; ++q) {
    const int G = t + 256 * q;
    const int kcfb = G >> 6, gl = G & 63;
    const int kc = kcfb >> 3, fb = kcfb & 7;
    const int gf = fb * 16 + (gl & 15);
    const int jloc = kc * 32 + (gl >> 4) * 8;
    const f16x8 v = *(const f16x8*)((const char*)tile + gf * 128 +
                                    (((unsigned)(jloc * 2)) ^ ((unsigned)((gf & 7) << 4))));
    ((f16x8*)Wfrag)[(size_t)(((j0 >> 5) + kc) * 8 + fb) * 64 + gl] = v;
  }
}

// ---------------------------------------------------------------------------
// K4: partial h' = P~ @ (Wh/Z) over this block's K-range -> part[kq].
//   P~pair = pk_max(pk_mul(rx2, ey), pk_mul(ry2, ez)) & maskLUT[bitbyte]
// BM=64, ksplit=8 (1024 cols, 16 steps of 64). 512 thr = 8 waves (2x4).
// Grid 1024 = 4 blocks/CU; launch_bounds(512,8) pins VGPR<=64 for occupancy.
// P via swizzled LDS (conflict-free b128); B-frags loaded per step (L2-hot);
// mb/ey/ez prefetched 2-3 steps ahead; barriers drain lgkmcnt only (T4); T5.
// ---------------------------------------------------------------------------
#define BARRIER_LDS()                                          \
  do {                                                         \
    __builtin_amdgcn_sched_barrier(0);                         \
    asm volatile("s_waitcnt lgkmcnt(0)" ::: "memory");         \
    __builtin_amdgcn_s_barrier();                              \
    __builtin_amdgcn_sched_barrier(0);                         \
  } while (0)

__global__ __launch_bounds__(512, 8) void k4_main(const uchar* __restrict__ bitsB,
                                                  const float2* __restrict__ r2,
                                                  const _Float16* __restrict__ ey16,
                                                  const _Float16* __restrict__ ez16,
                                                  const _Float16* __restrict__ Wfrag,
                                                  float* __restrict__ part) {
  __shared__ __align__(16) _Float16 P[2][64 * 64];  // 16 KB
  __shared__ uint32 lut[256][4];                    // 4 KB: byte -> 4 mask32
  const int t = threadIdx.x;
  const int rowtile = blockIdx.x >> 3;
  const int kq = blockIdx.x & 7;
  const int rowbase = rowtile * 64;
  const int koff = kq * 1024;

  if (t < 256) {
#pragma unroll
    for (int p = 0; p < 4; ++p) {
      const uint32 lo = ((t >> (2 * p)) & 1) ? 0x0000FFFFu : 0u;
      const uint32 hi = ((t >> (2 * p + 1)) & 1) ? 0xFFFF0000u : 0u;
      lut[t][p] = lo | hi;
    }
  }

  // ---- P-gen thread ids: row pr, 8 consecutive j at jq*8
  const int pr = t >> 3, jq = t & 7;
  const float2 rr = r2[rowbase + pr];
  const f16x2 rx2 = {(_Float16)rr.x, (_Float16)rr.x};
  const f16x2 ry2 = {(_Float16)rr.y, (_Float16)rr.y};
  const uchar* bp = bitsB + (size_t)(rowbase + pr) * (NN / 8) + (koff >> 3) + jq;
  const _Float16* eyp = ey16 + koff + jq * 8;
  const _Float16* ezp = ez16 + koff + jq * 8;
  char* const pdst0 = (char*)&P[0][0] + pr * 128 + (((unsigned)(jq * 16)) ^ ((unsigned)((pr & 7) << 4)));
  char* const pdst1 = (char*)&P[1][0] + pr * 128 + (((unsigned)(jq * 16)) ^ ((unsigned)((pr & 7) << 4)));

  // ---- MFMA ids
  const int lane = t & 63, wave = t >> 6;
  const int wr = wave >> 2, wc = wave & 3;
  const int kgrp = lane >> 4, l15 = lane & 15;
  const unsigned asw = (unsigned)((l15 & 7) << 4);
  const int ar0 = (wr * 32 + l15) * 128;
  const int ar1 = ar0 + 16 * 128;

  f32x4 acc00 = {0.f, 0.f, 0.f, 0.f}, acc01 = {0.f, 0.f, 0.f, 0.f};
  f32x4 acc10 = {0.f, 0.f, 0.f, 0.f}, acc11 = {0.f, 0.f, 0.f, 0.f};

  uchar mb0, mb1;
  uint4 ey0, ez0, ey1, ez1;
  f16x8 B00, B01, B10, B11;

#define LOADSMALL(S, MB, EY, EZ)                       \
  do {                                                 \
    MB = bp[(S) * 8];                                  \
    EY = *(const uint4*)(eyp + (S) * 64);              \
    EZ = *(const uint4*)(ezp + (S) * 64);              \
  } while (0)

#define LOADB(S)                                                                     \
  do {                                                                               \
    const _Float16* _b = Wfrag + ((size_t)((kq * 32 + (S) * 2) * 8 + wc * 2) * 64 + lane) * 8; \
    B00 = *(const f16x8*)(_b);                                                       \
    B01 = *(const f16x8*)(_b + 512);                                                 \
    B10 = *(const f16x8*)(_b + 4096);                                                \
    B11 = *(const f16x8*)(_b + 4096 + 512);                                          \
  } while (0)

#define PGEN(DST, MB, EY, EZ)                                                        \
  do {                                                                               \
    const uint4 _m = *(const uint4*)(&lut[MB][0]);                                   \
    const uint32 _eys[4] = {EY.x, EY.y, EY.z, EY.w};                                 \
    const uint32 _ezs[4] = {EZ.x, EZ.y, EZ.z, EZ.w};                                 \
    const uint32 _ms[4] = {_m.x, _m.y, _m.z, _m.w};                                  \
    uint32 _o[4];                                                                    \
    _Pragma("unroll") for (int _p = 0; _p < 4; ++_p) {                               \
      const f16x2 _a = __builtin_bit_cast(f16x2, _eys[_p]) * rx2;                    \
      const f16x2 _b2 = __builtin_bit_cast(f16x2, _ezs[_p]) * ry2;                   \
      const f16x2 _mx = __builtin_elementwise_max(_a, _b2);                          \
      _o[_p] = __builtin_bit_cast(uint32, _mx) & _ms[_p];                            \
    }                                                                                \
    uint4 _st; _st.x = _o[0]; _st.y = _o[1]; _st.z = _o[2]; _st.w = _o[3];           \
    *(uint4*)(DST) = _st;                                                            \
  } while (0)

#define DO_MFMA(BUF)                                                                 \
  do {                                                                               \
    const char* _Pb = (const char*)&P[BUF][0];                                       \
    const f16x8 a00 = *(const f16x8*)(_Pb + ar0 + ((((unsigned)(kgrp * 16))) ^ asw));        \
    const f16x8 a01 = *(const f16x8*)(_Pb + ar0 + (((unsigned)(64 + kgrp * 16)) ^ asw));     \
    const f16x8 a10 = *(const f16x8*)(_Pb + ar1 + ((((unsigned)(kgrp * 16))) ^ asw));        \
    const f16x8 a11 = *(const f16x8*)(_Pb + ar1 + (((unsigned)(64 + kgrp * 16)) ^ asw));     \
    __builtin_amdgcn_s_setprio(1);                                                   \
    acc00 = __builtin_amdgcn_mfma_f32_16x16x32_f16(a00, B00, acc00, 0, 0, 0);        \
    acc01 = __builtin_amdgcn_mfma_f32_16x16x32_f16(a00, B01, acc01, 0, 0, 0);        \
    acc10 = __builtin_amdgcn_mfma_f32_16x16x32_f16(a10, B00, acc10, 0, 0, 0);        \
    acc11 = __builtin_amdgcn_mfma_f32_16x16x32_f16(a10, B01, acc11, 0, 0, 0);        \
    acc00 = __builtin_amdgcn_mfma_f32_16x16x32_f16(a01, B10, acc00, 0, 0, 0);        \
    acc01 = __builtin_amdgcn_mfma_f32_16x16x32_f16(a01, B11, acc01, 0, 0, 0);        \
    acc10 = __builtin_amdgcn_mfma_f32_16x16x32_f16(a11, B10, acc10, 0, 0, 0);        \
    acc11 = __builtin_amdgcn_mfma_f32_16x16x32_f16(a11, B11, acc11, 0, 0, 0);        \
    __builtin_amdgcn_s_setprio(0);                                                   \
  } while (0)

  // ---- prologue
  LOADSMALL(0, mb0, ey0, ez0);
  LOADSMALL(1, mb1, ey1, ez1);
  __syncthreads();  // lut + first PGEN inputs ready
  PGEN(pdst0, mb0, ey0, ez0);
  LOADSMALL(2, mb0, ey0, ez0);
  BARRIER_LDS();

  for (int s = 0; s < 16; s += 2) {
    // ---- even body: step s
    LOADB(s);
    PGEN(pdst1, mb1, ey1, ez1);                        // P for step s+1
    if (s + 3 < 16) LOADSMALL(s + 3, mb1, ey1, ez1);
    DO_MFMA(0);
    BARRIER_LDS();
    // ---- odd body: step s+1
    LOADB(s + 1);
    if (s + 2 < 16) PGEN(pdst0, mb0, ey0, ez0);        // P for step s+2
    if (s + 4 < 16) LOADSMALL(s + 4, mb0, ey0, ez0);
    DO_MFMA(1);
    BARRIER_LDS();
  }

#undef LOADSMALL
#undef LOADB
#undef PGEN
#undef DO_MFMA

  // ---- epilogue: plain stores to this block's private partial buffer
  const int orow = rowbase + wr * 32 + kgrp * 4;
  const int ocol = wc * 32 + l15;
  float* aP = part + (size_t)kq * NN * FO + (size_t)orow * FO + ocol;
#pragma unroll
  for (int r = 0; r < 4; ++r) {
    aP[(size_t)r * FO] = acc00[r];
    aP[(size_t)r * FO + 16] = acc01[r];
    aP[(size_t)(16 + r) * FO] = acc10[r];
    aP[(size_t)(16 + r) * FO + 16] = acc11[r];
  }
}

// ---------------------------------------------------------------------------
// K5: out = elu(sum_q part[q] + corr), 8 partials
// ---------------------------------------------------------------------------
__global__ __launch_bounds__(256) void k5_fin(const float* __restrict__ part,
                                              const float* __restrict__ corr,
                                              float* __restrict__ out) {
  const int idx = blockIdx.x * 256 + threadIdx.x;  // float4 index, 262144 total
  float4 v = ((const float4*)part)[idx];
#pragma unroll
  for (int q = 1; q < 8; ++q) {
    const float4 p = ((const float4*)(part + (size_t)q * NN * FO))[idx];
    v.x += p.x; v.y += p.y; v.z += p.z; v.w += p.w;
  }
  const float4 c = ((const float4*)corr)[idx & 31];
  v.x += c.x; v.y += c.y; v.z += c.z; v.w += c.w;
  v.x = (v.x > 0.f) ? v.x : (expf(v.x) - 1.f);
  v.y = (v.y > 0.f) ? v.y : (expf(v.y) - 1.f);
  v.z = (v.z > 0.f) ? v.z : (expf(v.z) - 1.f);
  v.w = (v.w > 0.f) ? v.w : (expf(v.w) - 1.f);
  ((float4*)out)[idx] = v;
}

// ---------------------------------------------------------------------------
extern "C" void kernel_launch(void* const* d_in, const int* in_sizes, int n_in,
                              void* d_out, int out_size, void* d_ws, size_t ws_size,
                              hipStream_t stream) {
  const float* h = (const float*)d_in[0];
  const int* adj = (const int*)d_in[1];
  const float* W = (const float*)d_in[2];
  const float* b = (const float*)d_in[3];
  const float* a = (const float*)d_in[4];
  float* out = (float*)d_out;
  char* ws = (char*)d_ws;

  // workspace carve (~56 MB total; d_ws is ~1 GB per harness poison-fill size)
  float* Wh = (float*)(ws + 0);                                   // 4 MB  [k1..k3]
  _Float16* Wfrag = (_Float16*)(ws + 0x400000);                   // 2 MB  [k3..k4]
  uchar* bits = (uchar*)(ws + 0x600000);                          // 8 MB  [k2..k4]
  float2* zpart = (float2*)(ws + 0xE00000);                       // 8 MB  [k2..k3]
  float4* r4 = (float4*)(ws + 0x1600000);                         // 128 KB
  float4* c4 = (float4*)(ws + 0x1620000);                         // 128 KB
  float2* r2 = (float2*)(ws + 0x1640000);                         // 64 KB
  _Float16* ey16 = (_Float16*)(ws + 0x1650000);                   // 16 KB
  _Float16* ez16 = (_Float16*)(ws + 0x1654000);                   // 16 KB
  float* s2x = (float*)(ws + 0x1658000);                          // 32 KB
  float* corr = (float*)(ws + 0x1660000);                         // 512 B
  float* part = (float*)(ws + 0x1700000);                         // 32 MB [k4..k5]

  k1_wh<<<NN / 32, 256, 0, stream>>>(h, W, b, Wh);
  k1b_sv<<<NN / 4, 256, 0, stream>>>(Wh, a, r4, c4, r2, ey16, ez16, s2x, corr);
  k2_stats<<<512, 256, 0, stream>>>(adj, r4, s2x, bits, zpart);
  k3_scale<<<NN / 64, 256, 0, stream>>>(Wh, c4, zpart, Wfrag, corr);
  k4_main<<<1024, 512, 0, stream>>>(bits, r2, ey16, ez16, Wfrag, part);
  k5_fin<<<(NN * FO / 4) / 256, 256, 0, stream>>>(part, corr, out);
}

// Round 10
// 125.071 us; speedup vs baseline: 6.3715x; 2.0141x over previous
//
#include <hip/hip_runtime.h>

#define NN 8192
#define FI 256
#define FO 128
#define GAT_ALPHA 0.2f

typedef _Float16 f16x8 __attribute__((ext_vector_type(8)));
typedef _Float16 f16x2 __attribute__((ext_vector_type(2)));
typedef float f32x4 __attribute__((ext_vector_type(4)));
typedef unsigned char uchar;
typedef unsigned int uint32;

// ---------------------------------------------------------------------------
// K1: Wh[j][f] = sum_k h[j][k] * W[f][k] + b[f]   (fp32, LDS-tiled)
// ---------------------------------------------------------------------------
__global__ __launch_bounds__(256) void k1_wh(const float* __restrict__ h,
                                             const float* __restrict__ W,
                                             const float* __restrict__ bias,
                                             float* __restrict__ Wh) {
  __shared__ float hs[32][FI + 1];
  __shared__ float wt[32][FO];
  const int t = threadIdx.x;
  const int j0 = blockIdx.x * 32;
  {
    const int row = t >> 3, c0 = (t & 7) * 32;
    const float* src = h + (size_t)(j0 + row) * FI + c0;
#pragma unroll
    for (int e = 0; e < 8; ++e) {
      float4 v = *(const float4*)(src + 4 * e);
      hs[row][c0 + 4 * e + 0] = v.x;
      hs[row][c0 + 4 * e + 1] = v.y;
      hs[row][c0 + 4 * e + 2] = v.z;
      hs[row][c0 + 4 * e + 3] = v.w;
    }
  }
  const int f4 = (t & 31) * 4;
  const int r0 = (t >> 5) * 4;
  float acc[4][4];
#pragma unroll
  for (int r = 0; r < 4; ++r)
#pragma unroll
    for (int e = 0; e < 4; ++e) acc[r][e] = 0.f;

  for (int kc = 0; kc < FI; kc += 32) {
    __syncthreads();
    {
      const int f = t >> 1, kb = (t & 1) * 16;
      const float* wsrc = W + (size_t)f * FI + kc + kb;
#pragma unroll
      for (int e = 0; e < 16; ++e) wt[kb + e][f] = wsrc[e];
    }
    __syncthreads();
#pragma unroll
    for (int k = 0; k < 32; ++k) {
      const float4 wv = *(const float4*)&wt[k][f4];
      float hv[4];
#pragma unroll
      for (int r = 0; r < 4; ++r) hv[r] = hs[r0 + r][kc + k];
#pragma unroll
      for (int r = 0; r < 4; ++r) {
        acc[r][0] += hv[r] * wv.x;
        acc[r][1] += hv[r] * wv.y;
        acc[r][2] += hv[r] * wv.z;
        acc[r][3] += hv[r] * wv.w;
      }
    }
  }
  const float4 bv = *(const float4*)&bias[f4];
#pragma unroll
  for (int r = 0; r < 4; ++r) {
    float4 o;
    o.x = acc[r][0] + bv.x;
    o.y = acc[r][1] + bv.y;
    o.z = acc[r][2] + bv.z;
    o.w = acc[r][3] + bv.w;
    *(float4*)&Wh[(size_t)(j0 + r0 + r) * FO + f4] = o;
  }
}

// ---------------------------------------------------------------------------
// K1b: s1/s2 scores + exp tables; block 0 also zeroes corr (k3 runs later).
//  r4[j]=(s1, e^s1, e^.2s1, 0)  c4[j]=(s2, e^s2, e^.2s2, 0)
//  r2[j]=(e^s1, e^.2s1) f32     ey16[j]=f16 e^s2   ez16[j]=f16 e^.2s2
// ---------------------------------------------------------------------------
__global__ __launch_bounds__(256) void k1b_sv(const float* __restrict__ Wh,
                                              const float* __restrict__ a,
                                              float4* __restrict__ r4,
                                              float4* __restrict__ c4,
                                              float2* __restrict__ r2,
                                              _Float16* __restrict__ ey16,
                                              _Float16* __restrict__ ez16,
                                              float* __restrict__ s2x,
                                              float* __restrict__ corr) {
  if (blockIdx.x == 0 && threadIdx.x < FO) corr[threadIdx.x] = 0.f;
  const int lane = threadIdx.x & 63;
  const int j = blockIdx.x * 4 + (threadIdx.x >> 6);
  const float* row = Wh + (size_t)j * FO;
  const float w0 = row[lane], w1 = row[lane + 64];
  float s1 = w0 * a[lane] + w1 * a[lane + 64];
  float s2 = w0 * a[FO + lane] + w1 * a[FO + lane + 64];
#pragma unroll
  for (int o = 32; o >= 1; o >>= 1) {
    s1 += __shfl_xor(s1, o);
    s2 += __shfl_xor(s2, o);
  }
  if (lane == 0) {
    const float e1 = expf(s1), e1a = expf(GAT_ALPHA * s1);
    const float e2 = expf(s2), e2a = expf(GAT_ALPHA * s2);
    float4 rv; rv.x = s1; rv.y = e1; rv.z = e1a; rv.w = 0.f;
    float4 cv; cv.x = s2; cv.y = e2; cv.z = e2a; cv.w = 0.f;
    r4[j] = rv;
    c4[j] = cv;
    r2[j] = make_float2(e1, e1a);
    ey16[j] = (_Float16)e2;
    ez16[j] = (_Float16)e2a;
    s2x[j] = s2;
  }
}

// ---------------------------------------------------------------------------
// K2: single pass over adj (268 MB HBM floor). Thread owns 8 consecutive j
// (2x int4 = 32 B/lane), packs 8 activity bits into one byte, coalesced
// byte stores; 8 accP/accN register accumulators.
// ---------------------------------------------------------------------------
__global__ __launch_bounds__(256) void k2_stats(const int* __restrict__ adj,
                                                const float4* __restrict__ r4,
                                                const float* __restrict__ s2x,
                                                uchar* __restrict__ bitsB,
                                                float2* __restrict__ zpart) {
  __shared__ float4 rs[64];
  const int t = threadIdx.x;
  const int jc = blockIdx.x & 3;
  const int ic = blockIdx.x >> 2;
  const int i0 = ic * 64;
  const int j0 = jc * 2048 + t * 8;
  if (t < 64) rs[t] = r4[i0 + t];
  const float4 ca = *(const float4*)(s2x + j0);
  const float4 cb = *(const float4*)(s2x + j0 + 4);
  const float cx[8] = {ca.x, ca.y, ca.z, ca.w, cb.x, cb.y, cb.z, cb.w};
  float accP[8], accN[8];
#pragma unroll
  for (int e = 0; e < 8; ++e) { accP[e] = 0.f; accN[e] = 0.f; }
  __syncthreads();
  const int4* ap = (const int4*)(adj + (size_t)i0 * NN + j0);
  uchar* bp = bitsB + (size_t)i0 * (NN / 8) + jc * 256 + t;
  for (int ir = 0; ir < 64; ir += 8) {
    int4 av[8][2];
#pragma unroll
    for (int u = 0; u < 8; ++u) {
      av[u][0] = ap[(size_t)(ir + u) * (NN / 4)];
      av[u][1] = ap[(size_t)(ir + u) * (NN / 4) + 1];
    }
#pragma unroll
    for (int u = 0; u < 8; ++u) {
      const float4 ri = rs[ir + u];
      const int aa[8] = {av[u][0].x, av[u][0].y, av[u][0].z, av[u][0].w,
                         av[u][1].x, av[u][1].y, av[u][1].z, av[u][1].w};
      uint32 byte = 0;
#pragma unroll
      for (int e = 0; e < 8; ++e) {
        const bool act = aa[e] > 0;
        byte |= act ? (1u << e) : 0u;
        const bool pos = (ri.x + cx[e]) >= 0.f;
        accP[e] += (act && pos) ? ri.y : 0.f;
        accN[e] += (act && !pos) ? ri.z : 0.f;
      }
      bp[(size_t)(ir + u) * (NN / 8)] = (uchar)byte;
    }
  }
  float2* zp = zpart + (size_t)ic * NN + j0;
#pragma unroll
  for (int e = 0; e < 8; ++e) zp[e] = make_float2(accP[e], accN[e]);
}

// ---------------------------------------------------------------------------
// K3: Z_j from 128 partials; emit Wfrag in MFMA-B-fragment-major layout.
// Empty cols -> corr[f] (uniform softmax fix).
// ---------------------------------------------------------------------------
__global__ __launch_bounds__(256) void k3_scale(const float* __restrict__ Wh,
                                                const float4* __restrict__ c4,
                                                const float2* __restrict__ zpart,
                                                _Float16* __restrict__ Wfrag,
                                                float* __restrict__ corr) {
  __shared__ float rz[64];
  __shared__ int emp[64];
  __shared__ float2 psum[256];
  __shared__ __align__(16) _Float16 tile[FO * 64];
  const int t = threadIdx.x;
  const int j0 = blockIdx.x * 64;
  {
    const int jl = t & 63, q = t >> 6;
    float p = 0.f, n = 0.f;
    for (int ic = q * 32; ic < q * 32 + 32; ++ic) {
      const float2 z = zpart[(size_t)ic * NN + j0 + jl];
      p += z.x;
      n += z.y;
    }
    psum[t] = make_float2(p, n);
  }
  __syncthreads();
  if (t < 64) {
    const float p = psum[t].x + psum[64 + t].x + psum[128 + t].x + psum[192 + t].x;
    const float n = psum[t].y + psum[64 + t].y + psum[128 + t].y + psum[192 + t].y;
    const float4 cj = c4[j0 + t];
    const float Z = cj.y * p + cj.z * n;
    rz[t] = (Z > 0.f) ? 1.f / Z : 0.f;
    emp[t] = (Z > 0.f) ? 0 : 1;
  }
  __syncthreads();
  const int f = t & 127, half = t >> 7;
  const unsigned swf = (unsigned)((f & 7) << 4);
  for (int r = half; r < 64; r += 2) {
    const float v = Wh[(size_t)(j0 + r) * FO + f];
    *(_Float16*)((char*)tile + f * 128 + (((unsigned)(r * 2)) ^ swf)) =
        (_Float16)(v * rz[r]);
    if (emp[r]) atomicAdd(&corr[f], v * (1.f / 8192.f));
  }
  __syncthreads();
#pragma unroll
  for (int q = 0; q < 4; ++q) {
    const int G = t + 256 * q;
    const int kcfb = G >> 6, gl = G & 63;
    const int kc = kcfb >> 3, fb = kcfb & 7;
    const int gf = fb * 16 + (gl & 15);
    const int jloc = kc * 32 + (gl >> 4) * 8;
    const f16x8 v = *(const f16x8*)((const char*)tile + gf * 128 +
                                    (((unsigned)(jloc * 2)) ^ ((unsigned)((gf & 7) << 4))));
    ((f16x8*)Wfrag)[(size_t)(((j0 >> 5) + kc) * 8 + fb) * 64 + gl] = v;
  }
}

// ---------------------------------------------------------------------------
// K4: partial h' = P~ @ (Wh/Z) over this block's K-range -> part[kq].
//   P~pair = pk_max(pk_mul(rx2, ey), pk_mul(ry2, ez)) & maskLUT[bitbyte]
// Round-8 skeleton (measured 36us, VGPR=64, no spills): BM=64, ksplit=4
// (2048 cols, 32 steps of 64), 512 thr = 8 waves (2x4), launch_bounds(512,4),
// B-frags register double-buffered with distance-2 prefetch. Only PGEN is
// new (packed-f16 + LDS LUT, ~16 VALU vs ~52). Barriers drain lgkmcnt only.
// ---------------------------------------------------------------------------
#define BARRIER_LDS()                                          \
  do {                                                         \
    __builtin_amdgcn_sched_barrier(0);                         \
    asm volatile("s_waitcnt lgkmcnt(0)" ::: "memory");         \
    __builtin_amdgcn_s_barrier();                              \
    __builtin_amdgcn_sched_barrier(0);                         \
  } while (0)

__global__ __launch_bounds__(512, 4) void k4_main(const uchar* __restrict__ bitsB,
                                                  const float2* __restrict__ r2,
                                                  const _Float16* __restrict__ ey16,
                                                  const _Float16* __restrict__ ez16,
                                                  const _Float16* __restrict__ Wfrag,
                                                  float* __restrict__ part) {
  __shared__ __align__(16) _Float16 P[2][64 * 64];  // 16 KB
  __shared__ uint32 lut[256][4];                    // 4 KB: byte -> 4 mask32
  const int t = threadIdx.x;
  const int rowtile = blockIdx.x >> 2;
  const int kq = blockIdx.x & 3;
  const int rowbase = rowtile * 64;
  const int koff = kq * 2048;

  if (t < 256) {
#pragma unroll
    for (int p = 0; p < 4; ++p) {
      const uint32 lo = ((t >> (2 * p)) & 1) ? 0x0000FFFFu : 0u;
      const uint32 hi = ((t >> (2 * p + 1)) & 1) ? 0xFFFF0000u : 0u;
      lut[t][p] = lo | hi;
    }
  }

  // ---- P-gen thread ids: row pr, 8 consecutive j at jq*8
  const int pr = t >> 3, jq = t & 7;
  const float2 rr = r2[rowbase + pr];
  const f16x2 rx2 = {(_Float16)rr.x, (_Float16)rr.x};
  const f16x2 ry2 = {(_Float16)rr.y, (_Float16)rr.y};
  const uchar* bp = bitsB + (size_t)(rowbase + pr) * (NN / 8) + (koff >> 3) + jq;
  const _Float16* eyp = ey16 + koff + jq * 8;
  const _Float16* ezp = ez16 + koff + jq * 8;
  char* const pdst0 = (char*)&P[0][0] + pr * 128 + (((unsigned)(jq * 16)) ^ ((unsigned)((pr & 7) << 4)));
  char* const pdst1 = (char*)&P[1][0] + pr * 128 + (((unsigned)(jq * 16)) ^ ((unsigned)((pr & 7) << 4)));

  // ---- MFMA ids
  const int lane = t & 63, wave = t >> 6;
  const int wr = wave >> 2, wc = wave & 3;
  const int kgrp = lane >> 4, l15 = lane & 15;
  const unsigned asw = (unsigned)((l15 & 7) << 4);
  const int ar0 = (wr * 32 + l15) * 128;
  const int ar1 = ar0 + 16 * 128;

  f32x4 acc00 = {0.f, 0.f, 0.f, 0.f}, acc01 = {0.f, 0.f, 0.f, 0.f};
  f32x4 acc10 = {0.f, 0.f, 0.f, 0.f}, acc11 = {0.f, 0.f, 0.f, 0.f};

  uchar mb0, mb1;
  uint4 ey0, ez0, ey1, ez1;
  f16x8 B000, B001, B010, B011, B100, B101, B110, B111;

#define LOADALL(S, MB, EY, EZ, Bq00, Bq01, Bq10, Bq11)                              \
  do {                                                                              \
    MB = bp[(S) * 8];                                                               \
    EY = *(const uint4*)(eyp + (S) * 64);                                           \
    EZ = *(const uint4*)(ezp + (S) * 64);                                           \
    const _Float16* _b = Wfrag + ((size_t)((kq * 64 + (S) * 2) * 8 + wc * 2) * 64 + lane) * 8; \
    Bq00 = *(const f16x8*)(_b);                                                     \
    Bq01 = *(const f16x8*)(_b + 512);                                               \
    Bq10 = *(const f16x8*)(_b + 4096);                                              \
    Bq11 = *(const f16x8*)(_b + 4096 + 512);                                        \
  } while (0)

#define PGEN(DST, MB, EY, EZ)                                                        \
  do {                                                                               \
    const uint4 _m = *(const uint4*)(&lut[MB][0]);                                   \
    const uint32 _eys[4] = {EY.x, EY.y, EY.z, EY.w};                                 \
    const uint32 _ezs[4] = {EZ.x, EZ.y, EZ.z, EZ.w};                                 \
    const uint32 _ms[4] = {_m.x, _m.y, _m.z, _m.w};                                  \
    uint32 _o[4];                                                                    \
    _Pragma("unroll") for (int _p = 0; _p < 4; ++_p) {                               \
      const f16x2 _a = __builtin_bit_cast(f16x2, _eys[_p]) * rx2;                    \
      const f16x2 _b2 = __builtin_bit_cast(f16x2, _ezs[_p]) * ry2;                   \
      const f16x2 _mx = __builtin_elementwise_max(_a, _b2);                          \
      _o[_p] = __builtin_bit_cast(uint32, _mx) & _ms[_p];                            \
    }                                                                                \
    uint4 _st; _st.x = _o[0]; _st.y = _o[1]; _st.z = _o[2]; _st.w = _o[3];           \
    *(uint4*)(DST) = _st;                                                            \
  } while (0)

#define DO_MFMA(BUF, Bq00, Bq01, Bq10, Bq11)                                        \
  do {                                                                              \
    const char* _Pb = (const char*)&P[BUF][0];                                      \
    const f16x8 a00 = *(const f16x8*)(_Pb + ar0 + ((((unsigned)(kgrp * 16))) ^ asw));        \
    const f16x8 a01 = *(const f16x8*)(_Pb + ar0 + (((unsigned)(64 + kgrp * 16)) ^ asw));     \
    const f16x8 a10 = *(const f16x8*)(_Pb + ar1 + ((((unsigned)(kgrp * 16))) ^ asw));        \
    const f16x8 a11 = *(const f16x8*)(_Pb + ar1 + (((unsigned)(64 + kgrp * 16)) ^ asw));     \
    __builtin_amdgcn_s_setprio(1);                                                  \
    acc00 = __builtin_amdgcn_mfma_f32_16x16x32_f16(a00, Bq00, acc00, 0, 0, 0);      \
    acc01 = __builtin_amdgcn_mfma_f32_16x16x32_f16(a00, Bq01, acc01, 0, 0, 0);      \
    acc10 = __builtin_amdgcn_mfma_f32_16x16x32_f16(a10, Bq00, acc10, 0, 0, 0);      \
    acc11 = __builtin_amdgcn_mfma_f32_16x16x32_f16(a10, Bq01, acc11, 0, 0, 0);      \
    acc00 = __builtin_amdgcn_mfma_f32_16x16x32_f16(a01, Bq10, acc00, 0, 0, 0);      \
    acc01 = __builtin_amdgcn_mfma_f32_16x16x32_f16(a01, Bq11, acc01, 0, 0, 0);      \
    acc10 = __builtin_amdgcn_mfma_f32_16x16x32_f16(a11, Bq10, acc10, 0, 0, 0);      \
    acc11 = __builtin_amdgcn_mfma_f32_16x16x32_f16(a11, Bq11, acc11, 0, 0, 0);      \
    __builtin_amdgcn_s_setprio(0);                                                  \
  } while (0)

  // ---- prologue (lut written above; sync before first PGEN's lut read)
  LOADALL(0, mb0, ey0, ez0, B000, B001, B010, B011);
  LOADALL(1, mb1, ey1, ez1, B100, B101, B110, B111);
  __syncthreads();
  PGEN(pdst0, mb0, ey0, ez0);
  BARRIER_LDS();

  for (int s = 0; s < 32; s += 2) {
    // ---- even body: step s
    PGEN(pdst1, mb1, ey1, ez1);                       // P for step s+1
    DO_MFMA(0, B000, B001, B010, B011);               // step s
    if (s + 2 < 32) LOADALL(s + 2, mb0, ey0, ez0, B000, B001, B010, B011);
    BARRIER_LDS();
    // ---- odd body: step s+1
    DO_MFMA(1, B100, B101, B110, B111);               // step s+1
    if (s + 2 < 32) PGEN(pdst0, mb0, ey0, ez0);       // P for step s+2
    if (s + 3 < 32) LOADALL(s + 3, mb1, ey1, ez1, B100, B101, B110, B111);
    BARRIER_LDS();
  }

#undef LOADALL
#undef PGEN
#undef DO_MFMA

  // ---- epilogue: plain stores to this block's private partial buffer
  const int orow = rowbase + wr * 32 + kgrp * 4;
  const int ocol = wc * 32 + l15;
  float* aP = part + (size_t)kq * NN * FO + (size_t)orow * FO + ocol;
#pragma unroll
  for (int r = 0; r < 4; ++r) {
    aP[(size_t)r * FO] = acc00[r];
    aP[(size_t)r * FO + 16] = acc01[r];
    aP[(size_t)(16 + r) * FO] = acc10[r];
    aP[(size_t)(16 + r) * FO + 16] = acc11[r];
  }
}

// ---------------------------------------------------------------------------
// K5: out = elu(sum_q part[q] + corr), 4 partials
// ---------------------------------------------------------------------------
__global__ __launch_bounds__(256) void k5_fin(const float* __restrict__ part,
                                              const float* __restrict__ corr,
                                              float* __restrict__ out) {
  const int idx = blockIdx.x * 256 + threadIdx.x;  // float4 index, 262144 total
  const float4 p0 = ((const float4*)part)[idx];
  const float4 p1 = ((const float4*)(part + (size_t)NN * FO))[idx];
  const float4 p2 = ((const float4*)(part + (size_t)2 * NN * FO))[idx];
  const float4 p3 = ((const float4*)(part + (size_t)3 * NN * FO))[idx];
  const float4 c = ((const float4*)corr)[idx & 31];
  float4 v;
  v.x = p0.x + p1.x + p2.x + p3.x + c.x;
  v.y = p0.y + p1.y + p2.y + p3.y + c.y;
  v.z = p0.z + p1.z + p2.z + p3.z + c.z;
  v.w = p0.w + p1.w + p2.w + p3.w + c.w;
  v.x = (v.x > 0.f) ? v.x : (expf(v.x) - 1.f);
  v.y = (v.y > 0.f) ? v.y : (expf(v.y) - 1.f);
  v.z = (v.z > 0.f) ? v.z : (expf(v.z) - 1.f);
  v.w = (v.w > 0.f) ? v.w : (expf(v.w) - 1.f);
  ((float4*)out)[idx] = v;
}

// ---------------------------------------------------------------------------
extern "C" void kernel_launch(void* const* d_in, const int* in_sizes, int n_in,
                              void* d_out, int out_size, void* d_ws, size_t ws_size,
                              hipStream_t stream) {
  const float* h = (const float*)d_in[0];
  const int* adj = (const int*)d_in[1];
  const float* W = (const float*)d_in[2];
  const float* b = (const float*)d_in[3];
  const float* a = (const float*)d_in[4];
  float* out = (float*)d_out;
  char* ws = (char*)d_ws;

  // workspace carve (~40 MB total; d_ws is ~1 GB per harness poison-fill size)
  float* Wh = (float*)(ws + 0);                                   // 4 MB  [k1..k3]
  _Float16* Wfrag = (_Float16*)(ws + 0x400000);                   // 2 MB  [k3..k4]
  uchar* bits = (uchar*)(ws + 0x600000);                          // 8 MB  [k2..k4]
  float2* zpart = (float2*)(ws + 0xE00000);                       // 8 MB  [k2..k3]
  float4* r4 = (float4*)(ws + 0x1600000);                         // 128 KB
  float4* c4 = (float4*)(ws + 0x1620000);                         // 128 KB
  float2* r2 = (float2*)(ws + 0x1640000);                         // 64 KB
  _Float16* ey16 = (_Float16*)(ws + 0x1650000);                   // 16 KB
  _Float16* ez16 = (_Float16*)(ws + 0x1654000);                   // 16 KB
  float* s2x = (float*)(ws + 0x1658000);                          // 32 KB
  float* corr = (float*)(ws + 0x1660000);                         // 512 B
  float* part = (float*)(ws + 0x1700000);                         // 16 MB [k4..k5]

  k1_wh<<<NN / 32, 256, 0, stream>>>(h, W, b, Wh);
  k1b_sv<<<NN / 4, 256, 0, stream>>>(Wh, a, r4, c4, r2, ey16, ez16, s2x, corr);
  k2_stats<<<512, 256, 0, stream>>>(adj, r4, s2x, bits, zpart);
  k3_scale<<<NN / 64, 256, 0, stream>>>(Wh, c4, zpart, Wfrag, corr);
  k4_main<<<512, 512, 0, stream>>>(bits, r2, ey16, ez16, Wfrag, part);
  k5_fin<<<(NN * FO / 4) / 256, 256, 0, stream>>>(part, corr, out);
}

// Round 11
// 124.876 us; speedup vs baseline: 6.3814x; 1.0016x over previous
//
#include <hip/hip_runtime.h>

#define NN 8192
#define FI 256
#define FO 128
#define GAT_ALPHA 0.2f

typedef _Float16 f16x8 __attribute__((ext_vector_type(8)));
typedef _Float16 f16x2 __attribute__((ext_vector_type(2)));
typedef float f32x4 __attribute__((ext_vector_type(4)));
typedef unsigned char uchar;
typedef unsigned int uint32;

// ---------------------------------------------------------------------------
// K1: Wh[j][f] = sum_k h[j][k] * W[f][k] + b[f]  (fp32, LDS-tiled)
//   + fused k1b: s1/s2 scores + exp tables via 32-lane shfl reduction.
//  r4[j]=(s1, e^s1, e^.2s1, 0)  c4[j]=(s2, e^s2, e^.2s2, 0)
//  r2[j]=(e^s1, e^.2s1) f32     ey16[j]=f16 e^s2   ez16[j]=f16 e^.2s2
//  block 0 zeroes corr (k3 consumes it later in-stream).
// ---------------------------------------------------------------------------
__global__ __launch_bounds__(256) void k1_wh(const float* __restrict__ h,
                                             const float* __restrict__ W,
                                             const float* __restrict__ bias,
                                             const float* __restrict__ a,
                                             float* __restrict__ Wh,
                                             float4* __restrict__ r4,
                                             float4* __restrict__ c4,
                                             float2* __restrict__ r2,
                                             _Float16* __restrict__ ey16,
                                             _Float16* __restrict__ ez16,
                                             float* __restrict__ s2x,
                                             float* __restrict__ corr) {
  __shared__ float hs[32][FI + 1];
  __shared__ float wt[32][FO];
  const int t = threadIdx.x;
  const int j0 = blockIdx.x * 32;
  if (blockIdx.x == 0 && t < FO) corr[t] = 0.f;
  {
    const int row = t >> 3, c0 = (t & 7) * 32;
    const float* src = h + (size_t)(j0 + row) * FI + c0;
#pragma unroll
    for (int e = 0; e < 8; ++e) {
      float4 v = *(const float4*)(src + 4 * e);
      hs[row][c0 + 4 * e + 0] = v.x;
      hs[row][c0 + 4 * e + 1] = v.y;
      hs[row][c0 + 4 * e + 2] = v.z;
      hs[row][c0 + 4 * e + 3] = v.w;
    }
  }
  const int f4 = (t & 31) * 4;
  const int r0 = (t >> 5) * 4;
  float acc[4][4];
#pragma unroll
  for (int r = 0; r < 4; ++r)
#pragma unroll
    for (int e = 0; e < 4; ++e) acc[r][e] = 0.f;

  for (int kc = 0; kc < FI; kc += 32) {
    __syncthreads();
    {
      const int f = t >> 1, kb = (t & 1) * 16;
      const float* wsrc = W + (size_t)f * FI + kc + kb;
#pragma unroll
      for (int e = 0; e < 16; ++e) wt[kb + e][f] = wsrc[e];
    }
    __syncthreads();
#pragma unroll
    for (int k = 0; k < 32; ++k) {
      const float4 wv = *(const float4*)&wt[k][f4];
      float hv[4];
#pragma unroll
      for (int r = 0; r < 4; ++r) hv[r] = hs[r0 + r][kc + k];
#pragma unroll
      for (int r = 0; r < 4; ++r) {
        acc[r][0] += hv[r] * wv.x;
        acc[r][1] += hv[r] * wv.y;
        acc[r][2] += hv[r] * wv.z;
        acc[r][3] += hv[r] * wv.w;
      }
    }
  }
  const float4 bv = *(const float4*)&bias[f4];
  const float4 a1v = *(const float4*)&a[f4];
  const float4 a2v = *(const float4*)&a[FO + f4];
  float s1p[4], s2p[4];
#pragma unroll
  for (int r = 0; r < 4; ++r) {
    float4 o;
    o.x = acc[r][0] + bv.x;
    o.y = acc[r][1] + bv.y;
    o.z = acc[r][2] + bv.z;
    o.w = acc[r][3] + bv.w;
    *(float4*)&Wh[(size_t)(j0 + r0 + r) * FO + f4] = o;
    s1p[r] = o.x * a1v.x + o.y * a1v.y + o.z * a1v.z + o.w * a1v.w;
    s2p[r] = o.x * a2v.x + o.y * a2v.y + o.z * a2v.z + o.w * a2v.w;
  }
#pragma unroll
  for (int m = 16; m >= 1; m >>= 1) {
#pragma unroll
    for (int r = 0; r < 4; ++r) {
      s1p[r] += __shfl_xor(s1p[r], m);
      s2p[r] += __shfl_xor(s2p[r], m);
    }
  }
  if ((t & 31) == 0) {
#pragma unroll
    for (int r = 0; r < 4; ++r) {
      const int j = j0 + r0 + r;
      const float s1 = s1p[r], s2 = s2p[r];
      const float e1 = expf(s1), e1a = expf(GAT_ALPHA * s1);
      const float e2 = expf(s2), e2a = expf(GAT_ALPHA * s2);
      float4 rv; rv.x = s1; rv.y = e1; rv.z = e1a; rv.w = 0.f;
      float4 cv; cv.x = s2; cv.y = e2; cv.z = e2a; cv.w = 0.f;
      r4[j] = rv;
      c4[j] = cv;
      r2[j] = make_float2(e1, e1a);
      ey16[j] = (_Float16)e2;
      ez16[j] = (_Float16)e2a;
      s2x[j] = s2;
    }
  }
}

// ---------------------------------------------------------------------------
// K2: single pass over adj (268 MB HBM floor). Thread owns 8 consecutive j
// (2x int4 = 32 B/lane), packs 8 activity bits into one byte, coalesced
// byte stores; 8 accP/accN register accumulators.
// ---------------------------------------------------------------------------
__global__ __launch_bounds__(256) void k2_stats(const int* __restrict__ adj,
                                                const float4* __restrict__ r4,
                                                const float* __restrict__ s2x,
                                                uchar* __restrict__ bitsB,
                                                float2* __restrict__ zpart) {
  __shared__ float4 rs[64];
  const int t = threadIdx.x;
  const int jc = blockIdx.x & 3;
  const int ic = blockIdx.x >> 2;
  const int i0 = ic * 64;
  const int j0 = jc * 2048 + t * 8;
  if (t < 64) rs[t] = r4[i0 + t];
  const float4 ca = *(const float4*)(s2x + j0);
  const float4 cb = *(const float4*)(s2x + j0 + 4);
  const float cx[8] = {ca.x, ca.y, ca.z, ca.w, cb.x, cb.y, cb.z, cb.w};
  float accP[8], accN[8];
#pragma unroll
  for (int e = 0; e < 8; ++e) { accP[e] = 0.f; accN[e] = 0.f; }
  __syncthreads();
  const int4* ap = (const int4*)(adj + (size_t)i0 * NN + j0);
  uchar* bp = bitsB + (size_t)i0 * (NN / 8) + jc * 256 + t;
  for (int ir = 0; ir < 64; ir += 8) {
    int4 av[8][2];
#pragma unroll
    for (int u = 0; u < 8; ++u) {
      av[u][0] = ap[(size_t)(ir + u) * (NN / 4)];
      av[u][1] = ap[(size_t)(ir + u) * (NN / 4) + 1];
    }
#pragma unroll
    for (int u = 0; u < 8; ++u) {
      const float4 ri = rs[ir + u];
      const int aa[8] = {av[u][0].x, av[u][0].y, av[u][0].z, av[u][0].w,
                         av[u][1].x, av[u][1].y, av[u][1].z, av[u][1].w};
      uint32 byte = 0;
#pragma unroll
      for (int e = 0; e < 8; ++e) {
        const bool act = aa[e] > 0;
        byte |= act ? (1u << e) : 0u;
        const bool pos = (ri.x + cx[e]) >= 0.f;
        accP[e] += (act && pos) ? ri.y : 0.f;
        accN[e] += (act && !pos) ? ri.z : 0.f;
      }
      bp[(size_t)(ir + u) * (NN / 8)] = (uchar)byte;
    }
  }
  float2* zp = zpart + (size_t)ic * NN + j0;
#pragma unroll
  for (int e = 0; e < 8; ++e) zp[e] = make_float2(accP[e], accN[e]);
}

// ---------------------------------------------------------------------------
// K3: Z_j from 128 partials; emit Wfrag in MFMA-B-fragment-major layout.
// Empty cols -> corr[f] (uniform softmax fix).
// ---------------------------------------------------------------------------
__global__ __launch_bounds__(256) void k3_scale(const float* __restrict__ Wh,
                                                const float4* __restrict__ c4,
                                                const float2* __restrict__ zpart,
                                                _Float16* __restrict__ Wfrag,
                                                float* __restrict__ corr) {
  __shared__ float rz[64];
  __shared__ int emp[64];
  __shared__ float2 psum[256];
  __shared__ __align__(16) _Float16 tile[FO * 64];
  const int t = threadIdx.x;
  const int j0 = blockIdx.x * 64;
  {
    const int jl = t & 63, q = t >> 6;
    float p = 0.f, n = 0.f;
    for (int ic = q * 32; ic < q * 32 + 32; ++ic) {
      const float2 z = zpart[(size_t)ic * NN + j0 + jl];
      p += z.x;
      n += z.y;
    }
    psum[t] = make_float2(p, n);
  }
  __syncthreads();
  if (t < 64) {
    const float p = psum[t].x + psum[64 + t].x + psum[128 + t].x + psum[192 + t].x;
    const float n = psum[t].y + psum[64 + t].y + psum[128 + t].y + psum[192 + t].y;
    const float4 cj = c4[j0 + t];
    const float Z = cj.y * p + cj.z * n;
    rz[t] = (Z > 0.f) ? 1.f / Z : 0.f;
    emp[t] = (Z > 0.f) ? 0 : 1;
  }
  __syncthreads();
  const int f = t & 127, half = t >> 7;
  const unsigned swf = (unsigned)((f & 7) << 4);
  for (int r = half; r < 64; r += 2) {
    const float v = Wh[(size_t)(j0 + r) * FO + f];
    *(_Float16*)((char*)tile + f * 128 + (((unsigned)(r * 2)) ^ swf)) =
        (_Float16)(v * rz[r]);
    if (emp[r]) atomicAdd(&corr[f], v * (1.f / 8192.f));
  }
  __syncthreads();
#pragma unroll
  for (int q = 0; q < 4; ++q) {
    const int G = t + 256 * q;
    const int kcfb = G >> 6, gl = G & 63;
    const int kc = kcfb >> 3, fb = kcfb & 7;
    const int gf = fb * 16 + (gl & 15);
    const int jloc = kc * 32 + (gl >> 4) * 8;
    const f16x8 v = *(const f16x8*)((const char*)tile + gf * 128 +
                                    (((unsigned)(jloc * 2)) ^ ((unsigned)((gf & 7) << 4))));
    ((f16x8*)Wfrag)[(size_t)(((j0 >> 5) + kc) * 8 + fb) * 64 + gl] = v;
  }
}

// ---------------------------------------------------------------------------
// K4: partial h' = P~ @ (Wh/Z) over this block's K-range -> part[kq].
//   P~pair = pk_max(pk_mul(rx2, ey), pk_mul(ry2, ez)) & maskLUT[bitbyte]
// BM=32, 256 thr = 4 waves (1x4), ksplit=4 (2048 cols, 32 steps of 64).
// Grid 1024 -> 4-5 independent blocks/CU (latency hiding across blocks;
// barrier couples only 4 waves). LDS 12 KB. B-frags register
// double-buffered distance-2; barriers drain lgkmcnt only; setprio on MFMA.
// ---------------------------------------------------------------------------
#define BARRIER_LDS()                                          \
  do {                                                         \
    __builtin_amdgcn_sched_barrier(0);                         \
    asm volatile("s_waitcnt lgkmcnt(0)" ::: "memory");         \
    __builtin_amdgcn_s_barrier();                              \
    __builtin_amdgcn_sched_barrier(0);                         \
  } while (0)

__global__ __launch_bounds__(256) void k4_main(const uchar* __restrict__ bitsB,
                                               const float2* __restrict__ r2,
                                               const _Float16* __restrict__ ey16,
                                               const _Float16* __restrict__ ez16,
                                               const _Float16* __restrict__ Wfrag,
                                               float* __restrict__ part) {
  __shared__ __align__(16) _Float16 P[2][32 * 64];  // 8 KB
  __shared__ uint32 lut[256][4];                    // 4 KB: byte -> 4 mask32
  const int t = threadIdx.x;
  const int rowtile = blockIdx.x >> 2;
  const int kq = blockIdx.x & 3;
  const int rowbase = rowtile * 32;
  const int koff = kq * 2048;

  {
#pragma unroll
    for (int p = 0; p < 4; ++p) {
      const uint32 lo = ((t >> (2 * p)) & 1) ? 0x0000FFFFu : 0u;
      const uint32 hi = ((t >> (2 * p + 1)) & 1) ? 0xFFFF0000u : 0u;
      lut[t][p] = lo | hi;
    }
  }

  // ---- P-gen thread ids: row pr (0..31), 8 consecutive j at jq*8
  const int pr = t >> 3, jq = t & 7;
  const float2 rr = r2[rowbase + pr];
  const f16x2 rx2 = {(_Float16)rr.x, (_Float16)rr.x};
  const f16x2 ry2 = {(_Float16)rr.y, (_Float16)rr.y};
  const uchar* bp = bitsB + (size_t)(rowbase + pr) * (NN / 8) + (koff >> 3) + jq;
  const _Float16* eyp = ey16 + koff + jq * 8;
  const _Float16* ezp = ez16 + koff + jq * 8;
  char* const pdst0 = (char*)&P[0][0] + pr * 128 + (((unsigned)(jq * 16)) ^ ((unsigned)((pr & 7) << 4)));
  char* const pdst1 = (char*)&P[1][0] + pr * 128 + (((unsigned)(jq * 16)) ^ ((unsigned)((pr & 7) << 4)));

  // ---- MFMA ids: wave = col-tile (4 waves cover 128 cols)
  const int lane = t & 63, wc = t >> 6;
  const int kgrp = lane >> 4, l15 = lane & 15;
  const unsigned asw = (unsigned)((l15 & 7) << 4);
  const int ar0 = l15 * 128;          // rows 0-15
  const int ar1 = ar0 + 16 * 128;     // rows 16-31

  f32x4 acc00 = {0.f, 0.f, 0.f, 0.f}, acc01 = {0.f, 0.f, 0.f, 0.f};
  f32x4 acc10 = {0.f, 0.f, 0.f, 0.f}, acc11 = {0.f, 0.f, 0.f, 0.f};

  uchar mb0, mb1;
  uint4 ey0, ez0, ey1, ez1;
  f16x8 B000, B001, B010, B011, B100, B101, B110, B111;

#define LOADALL(S, MB, EY, EZ, Bq00, Bq01, Bq10, Bq11)                              \
  do {                                                                              \
    MB = bp[(S) * 8];                                                               \
    EY = *(const uint4*)(eyp + (S) * 64);                                           \
    EZ = *(const uint4*)(ezp + (S) * 64);                                           \
    const _Float16* _b = Wfrag + ((size_t)((kq * 64 + (S) * 2) * 8 + wc * 2) * 64 + lane) * 8; \
    Bq00 = *(const f16x8*)(_b);                                                     \
    Bq01 = *(const f16x8*)(_b + 512);                                               \
    Bq10 = *(const f16x8*)(_b + 4096);                                              \
    Bq11 = *(const f16x8*)(_b + 4096 + 512);                                        \
  } while (0)

#define PGEN(DST, MB, EY, EZ)                                                        \
  do {                                                                               \
    const uint4 _m = *(const uint4*)(&lut[MB][0]);                                   \
    const uint32 _eys[4] = {EY.x, EY.y, EY.z, EY.w};                                 \
    const uint32 _ezs[4] = {EZ.x, EZ.y, EZ.z, EZ.w};                                 \
    const uint32 _ms[4] = {_m.x, _m.y, _m.z, _m.w};                                  \
    uint32 _o[4];                                                                    \
    _Pragma("unroll") for (int _p = 0; _p < 4; ++_p) {                               \
      const f16x2 _a = __builtin_bit_cast(f16x2, _eys[_p]) * rx2;                    \
      const f16x2 _b2 = __builtin_bit_cast(f16x2, _ezs[_p]) * ry2;                   \
      const f16x2 _mx = __builtin_elementwise_max(_a, _b2);                          \
      _o[_p] = __builtin_bit_cast(uint32, _mx) & _ms[_p];                            \
    }                                                                                \
    uint4 _st; _st.x = _o[0]; _st.y = _o[1]; _st.z = _o[2]; _st.w = _o[3];           \
    *(uint4*)(DST) = _st;                                                            \
  } while (0)

#define DO_MFMA(BUF, Bq00, Bq01, Bq10, Bq11)                                        \
  do {                                                                              \
    const char* _Pb = (const char*)&P[BUF][0];                                      \
    const f16x8 a00 = *(const f16x8*)(_Pb + ar0 + ((((unsigned)(kgrp * 16))) ^ asw));        \
    const f16x8 a01 = *(const f16x8*)(_Pb + ar0 + (((unsigned)(64 + kgrp * 16)) ^ asw));     \
    const f16x8 a10 = *(const f16x8*)(_Pb + ar1 + ((((unsigned)(kgrp * 16))) ^ asw));        \
    const f16x8 a11 = *(const f16x8*)(_Pb + ar1 + (((unsigned)(64 + kgrp * 16)) ^ asw));     \
    __builtin_amdgcn_s_setprio(1);                                                  \
    acc00 = __builtin_amdgcn_mfma_f32_16x16x32_f16(a00, Bq00, acc00, 0, 0, 0);      \
    acc01 = __builtin_amdgcn_mfma_f32_16x16x32_f16(a00, Bq01, acc01, 0, 0, 0);      \
    acc10 = __builtin_amdgcn_mfma_f32_16x16x32_f16(a10, Bq00, acc10, 0, 0, 0);      \
    acc11 = __builtin_amdgcn_mfma_f32_16x16x32_f16(a10, Bq01, acc11, 0, 0, 0);      \
    acc00 = __builtin_amdgcn_mfma_f32_16x16x32_f16(a01, Bq10, acc00, 0, 0, 0);      \
    acc01 = __builtin_amdgcn_mfma_f32_16x16x32_f16(a01, Bq11, acc01, 0, 0, 0);      \
    acc10 = __builtin_amdgcn_mfma_f32_16x16x32_f16(a11, Bq10, acc10, 0, 0, 0);      \
    acc11 = __builtin_amdgcn_mfma_f32_16x16x32_f16(a11, Bq11, acc11, 0, 0, 0);      \
    __builtin_amdgcn_s_setprio(0);                                                  \
  } while (0)

  // ---- prologue (sync covers lut writes before first PGEN lut read)
  LOADALL(0, mb0, ey0, ez0, B000, B001, B010, B011);
  LOADALL(1, mb1, ey1, ez1, B100, B101, B110, B111);
  __syncthreads();
  PGEN(pdst0, mb0, ey0, ez0);
  BARRIER_LDS();

  for (int s = 0; s < 32; s += 2) {
    // ---- even body: step s
    PGEN(pdst1, mb1, ey1, ez1);                       // P for step s+1
    DO_MFMA(0, B000, B001, B010, B011);               // step s
    if (s + 2 < 32) LOADALL(s + 2, mb0, ey0, ez0, B000, B001, B010, B011);
    BARRIER_LDS();
    // ---- odd body: step s+1
    DO_MFMA(1, B100, B101, B110, B111);               // step s+1
    if (s + 2 < 32) PGEN(pdst0, mb0, ey0, ez0);       // P for step s+2
    if (s + 3 < 32) LOADALL(s + 3, mb1, ey1, ez1, B100, B101, B110, B111);
    BARRIER_LDS();
  }

#undef LOADALL
#undef PGEN
#undef DO_MFMA

  // ---- epilogue: plain stores to this block's private partial buffer
  const int orow = rowbase + kgrp * 4;
  const int ocol = wc * 32 + l15;
  float* aP = part + (size_t)kq * NN * FO + (size_t)orow * FO + ocol;
#pragma unroll
  for (int r = 0; r < 4; ++r) {
    aP[(size_t)r * FO] = acc00[r];
    aP[(size_t)r * FO + 16] = acc01[r];
    aP[(size_t)(16 + r) * FO] = acc10[r];
    aP[(size_t)(16 + r) * FO + 16] = acc11[r];
  }
}

// ---------------------------------------------------------------------------
// K5: out = elu(sum_q part[q] + corr), 4 partials
// ---------------------------------------------------------------------------
__global__ __launch_bounds__(256) void k5_fin(const float* __restrict__ part,
                                              const float* __restrict__ corr,
                                              float* __restrict__ out) {
  const int idx = blockIdx.x * 256 + threadIdx.x;  // float4 index, 262144 total
  const float4 p0 = ((const float4*)part)[idx];
  const float4 p1 = ((const float4*)(part + (size_t)NN * FO))[idx];
  const float4 p2 = ((const float4*)(part + (size_t)2 * NN * FO))[idx];
  const float4 p3 = ((const float4*)(part + (size_t)3 * NN * FO))[idx];
  const float4 c = ((const float4*)corr)[idx & 31];
  float4 v;
  v.x = p0.x + p1.x + p2.x + p3.x + c.x;
  v.y = p0.y + p1.y + p2.y + p3.y + c.y;
  v.z = p0.z + p1.z + p2.z + p3.z + c.z;
  v.w = p0.w + p1.w + p2.w + p3.w + c.w;
  v.x = (v.x > 0.f) ? v.x : (expf(v.x) - 1.f);
  v.y = (v.y > 0.f) ? v.y : (expf(v.y) - 1.f);
  v.z = (v.z > 0.f) ? v.z : (expf(v.z) - 1.f);
  v.w = (v.w > 0.f) ? v.w : (expf(v.w) - 1.f);
  ((float4*)out)[idx] = v;
}

// ---------------------------------------------------------------------------
extern "C" void kernel_launch(void* const* d_in, const int* in_sizes, int n_in,
                              void* d_out, int out_size, void* d_ws, size_t ws_size,
                              hipStream_t stream) {
  const float* h = (const float*)d_in[0];
  const int* adj = (const int*)d_in[1];
  const float* W = (const float*)d_in[2];
  const float* b = (const float*)d_in[3];
  const float* a = (const float*)d_in[4];
  float* out = (float*)d_out;
  char* ws = (char*)d_ws;

  // workspace carve (~40 MB total; d_ws is ~1 GB per harness poison-fill size)
  float* Wh = (float*)(ws + 0);                                   // 4 MB  [k1..k3]
  _Float16* Wfrag = (_Float16*)(ws + 0x400000);                   // 2 MB  [k3..k4]
  uchar* bits = (uchar*)(ws + 0x600000);                          // 8 MB  [k2..k4]
  float2* zpart = (float2*)(ws + 0xE00000);                       // 8 MB  [k2..k3]
  float4* r4 = (float4*)(ws + 0x1600000);                         // 128 KB
  float4* c4 = (float4*)(ws + 0x1620000);                         // 128 KB
  float2* r2 = (float2*)(ws + 0x1640000);                         // 64 KB
  _Float16* ey16 = (_Float16*)(ws + 0x1650000);                   // 16 KB
  _Float16* ez16 = (_Float16*)(ws + 0x1654000);                   // 16 KB
  float* s2x = (float*)(ws + 0x1658000);                          // 32 KB
  float* corr = (float*)(ws + 0x1660000);                         // 512 B
  float* part = (float*)(ws + 0x1700000);                         // 16 MB [k4..k5]

  k1_wh<<<NN / 32, 256, 0, stream>>>(h, W, b, a, Wh, r4, c4, r2, ey16, ez16, s2x, corr);
  k2_stats<<<512, 256, 0, stream>>>(adj, r4, s2x, bits, zpart);
  k3_scale<<<NN / 64, 256, 0, stream>>>(Wh, c4, zpart, Wfrag, corr);
  k4_main<<<1024, 256, 0, stream>>>(bits, r2, ey16, ez16, Wfrag, part);
  k5_fin<<<(NN * FO / 4) / 256, 256, 0, stream>>>(part, corr, out);
}